// Round 6
// baseline (171.915 us; speedup 1.0000x reference)
//
#include <hip/hip_runtime.h>
#include <hip/hip_cooperative_groups.h>

namespace cg = cooperative_groups;

#define NPTS 16384
#define NBATCH 256

__device__ __forceinline__ float4 ld4(const float* p) {
  return *reinterpret_cast<const float4*>(p);
}

// ======================= Cooperative single-pass =========================
constexpr int C_THREADS = 256;               // 4 waves
constexpr int C_EPT     = 16;                // 16 points per thread
constexpr int C_CHUNK   = C_THREADS * C_EPT; // 4096 points per block
constexpr int C_NCH     = NPTS / C_CHUNK;    // 4 chunks per row
constexpr int C_NBLK    = NBATCH * C_NCH;    // 1024 blocks (4/CU resident)
constexpr int C_NW      = C_THREADS / 64;    // 4

__global__ __launch_bounds__(C_THREADS, 4) void coop_kernel(
    const float* __restrict__ o3, const float* __restrict__ s3,
    const float* __restrict__ o2, const float* __restrict__ s2,
    const float* __restrict__ df, float4* __restrict__ agg,
    float* __restrict__ out) {
  const int blk = blockIdx.x;
  const int b = blk >> 2;          // batch row
  const int c = blk & 3;           // chunk within row
  const int t = threadIdx.x;
  const int lane = t & 63;
  const int wave = t >> 6;

  const float* r3p = s3 + (size_t)b * 3 * NPTS;
  const float* t3p = r3p + NPTS;
  const float* p3p = r3p + 2 * NPTS;
  const float* r2p = s2 + (size_t)b * 3 * NPTS;
  const float* t2p = r2p + NPTS;
  const float* p2p = r2p + 2 * NPTS;
  const float* dtp = df + (size_t)b * 2 * NPTS;
  const float* dpp = dtp + NPTS;

  const int idx = c * C_CHUNK + t * C_EPT;

  // ---- Phase 1: diffs + thread-local prefix, kept in registers ----
  float px[C_EPT], py[C_EPT], pz[C_EPT];
  float sx = 0.f, sy = 0.f, sz = 0.f;
  #pragma unroll
  for (int g = 0; g < C_EPT / 4; ++g) {
    float4 R3 = ld4(r3p + idx + 4 * g), T3 = ld4(t3p + idx + 4 * g);
    float4 P3 = ld4(p3p + idx + 4 * g), R2 = ld4(r2p + idx + 4 * g);
    float4 T2 = ld4(t2p + idx + 4 * g), P2 = ld4(p2p + idx + 4 * g);
    float4 DT = ld4(dtp + idx + 4 * g), DP = ld4(dpp + idx + 4 * g);
    #pragma unroll
    for (int k = 0; k < 4; ++k) {
      const int e = 4 * g + k;
      float r3v = ((const float*)&R3)[k];
      float th3 = ((const float*)&T3)[k] + ((const float*)&DT)[k];
      float ph3 = ((const float*)&P3)[k] + ((const float*)&DP)[k];
      float r2v = ((const float*)&R2)[k];
      float th2 = ((const float*)&T2)[k];
      float ph2 = ((const float*)&P2)[k];
      float st3 = __sinf(th3), ct3 = __cosf(th3);
      float sp3 = __sinf(ph3), cp3 = __cosf(ph3);
      float st2 = __sinf(th2), ct2 = __cosf(th2);
      float sp2 = __sinf(ph2), cp2 = __cosf(ph2);
      sx += r3v * st3 * cp3 - r2v * st2 * cp2; px[e] = sx;
      sy += r3v * st3 * sp3 - r2v * st2 * sp2; py[e] = sy;
      sz += r3v * ct3 - r2v * ct2;             pz[e] = sz;
    }
  }

  // wave-level inclusive scan of thread totals
  float ix = sx, iy = sy, iz = sz;
  #pragma unroll
  for (int off = 1; off < 64; off <<= 1) {
    float ax = __shfl_up(ix, off, 64);
    float ay = __shfl_up(iy, off, 64);
    float az = __shfl_up(iz, off, 64);
    if (lane >= off) { ix += ax; iy += ay; iz += az; }
  }
  const float exs = ix - sx, eys = iy - sy, ezs = iz - sz;

  __shared__ float wtot[3][C_NW];
  __shared__ float redbuf[C_NW];
  if (lane == 63) { wtot[0][wave] = ix; wtot[1][wave] = iy; wtot[2][wave] = iz; }
  __syncthreads();

  float wx = 0.f, wy = 0.f, wz = 0.f;   // offset of previous waves
  float agx = 0.f, agy = 0.f, agz = 0.f;// block aggregate
  #pragma unroll
  for (int w = 0; w < C_NW; ++w) {
    float vx = wtot[0][w], vy = wtot[1][w], vz = wtot[2][w];
    if (w < wave) { wx += vx; wy += vy; wz += vz; }
    agx += vx; agy += vy; agz += vz;
  }
  if (t == 0) agg[blk] = make_float4(agx, agy, agz, 0.f);

  const float boffx = wx + exs, boffy = wy + eys, boffz = wz + ezs;

  // ---- grid-wide sync: aggregates now globally visible ----
  cg::this_grid().sync();

  // ---- Phase 2: carry + in-register prefixes -> abs-sum ----
  const float ox = o3[b * 3 + 0] - o2[b * 3 + 0];
  const float oy = o3[b * 3 + 1] - o2[b * 3 + 1];
  const float oz = o3[b * 3 + 2] - o2[b * 3 + 2];
  float carx = ox, cary = oy, carz = oz;
  for (int cc = 0; cc < c; ++cc) {      // <=3 uniform L2-hot loads
    float4 a = agg[(b << 2) + cc];
    carx += a.x; cary += a.y; carz += a.z;
  }

  const float bx = carx + boffx;
  const float by = cary + boffy;
  const float bz = carz + boffz;

  float acc = 0.f;
  #pragma unroll
  for (int e = 0; e < C_EPT; ++e) {
    acc += fabsf(bx + px[e]) + fabsf(by + py[e]) + fabsf(bz + pz[e]);
  }
  if (c == 0 && t == 0) acc += fabsf(ox) + fabsf(oy) + fabsf(oz);  // j=0 term

  #pragma unroll
  for (int off = 32; off > 0; off >>= 1) acc += __shfl_down(acc, off, 64);
  if (lane == 0) redbuf[wave] = acc;
  __syncthreads();
  if (t == 0) {
    float s = 0.f;
    #pragma unroll
    for (int w = 0; w < C_NW; ++w) s += redbuf[w];
    atomicAdd(out, s * (1.0f / (float)(NPTS + 1)));
  }
}

// ======================= Pipeline A: diff-store fallback ==================
constexpr int A_THREADS = 256;
constexpr int A_EPT     = 8;
constexpr int A_CHUNK   = A_THREADS * A_EPT; // 2048
constexpr int A_NCH     = NPTS / A_CHUNK;    // 8
constexpr int A_NBLK    = NBATCH * A_NCH;    // 2048
constexpr int A_NW      = A_THREADS / 64;    // 4
constexpr size_t NPOINTS = (size_t)NBATCH * NPTS;
constexpr size_t WS_AGG_OFF     = 0;
constexpr size_t WS_PARTIAL_OFF = 32 * 1024;
constexpr size_t WS_DX_OFF      = 64 * 1024;
constexpr size_t WS_NEED = WS_DX_OFF + 3 * NPOINTS * sizeof(float);

__global__ __launch_bounds__(A_THREADS) void k1_diff(
    const float* __restrict__ s3, const float* __restrict__ s2,
    const float* __restrict__ df, float4* __restrict__ agg,
    float* __restrict__ dx, float* __restrict__ dy, float* __restrict__ dz) {
  const int blk = blockIdx.x;
  const int b = blk >> 3;
  const int c = blk & (A_NCH - 1);
  const int t = threadIdx.x;
  const int lane = t & 63;
  const int wave = t >> 6;

  const float* r3p = s3 + (size_t)b * 3 * NPTS;
  const float* t3p = r3p + NPTS;
  const float* p3p = r3p + 2 * NPTS;
  const float* r2p = s2 + (size_t)b * 3 * NPTS;
  const float* t2p = r2p + NPTS;
  const float* p2p = r2p + 2 * NPTS;
  const float* dtp = df + (size_t)b * 2 * NPTS;
  const float* dpp = dtp + NPTS;

  const int idx = c * A_CHUNK + t * A_EPT;
  const size_t gidx = (size_t)b * NPTS + idx;

  float4 R3[2], T3[2], P3[2], R2[2], T2[2], P2[2], DT[2], DP[2];
  #pragma unroll
  for (int g = 0; g < 2; ++g) {
    R3[g] = ld4(r3p + idx + 4 * g);
    T3[g] = ld4(t3p + idx + 4 * g);
    P3[g] = ld4(p3p + idx + 4 * g);
    R2[g] = ld4(r2p + idx + 4 * g);
    T2[g] = ld4(t2p + idx + 4 * g);
    P2[g] = ld4(p2p + idx + 4 * g);
    DT[g] = ld4(dtp + idx + 4 * g);
    DP[g] = ld4(dpp + idx + 4 * g);
  }

  float dxv[A_EPT], dyv[A_EPT], dzv[A_EPT];
  float sx = 0.f, sy = 0.f, sz = 0.f;
  #pragma unroll
  for (int e = 0; e < A_EPT; ++e) {
    const int g = e >> 2, k = e & 3;
    float r3v = ((const float*)&R3[g])[k];
    float th3 = ((const float*)&T3[g])[k] + ((const float*)&DT[g])[k];
    float ph3 = ((const float*)&P3[g])[k] + ((const float*)&DP[g])[k];
    float r2v = ((const float*)&R2[g])[k];
    float th2 = ((const float*)&T2[g])[k];
    float ph2 = ((const float*)&P2[g])[k];
    float st3 = __sinf(th3), ct3 = __cosf(th3);
    float sp3 = __sinf(ph3), cp3 = __cosf(ph3);
    float st2 = __sinf(th2), ct2 = __cosf(th2);
    float sp2 = __sinf(ph2), cp2 = __cosf(ph2);
    dxv[e] = r3v * st3 * cp3 - r2v * st2 * cp2;
    dyv[e] = r3v * st3 * sp3 - r2v * st2 * sp2;
    dzv[e] = r3v * ct3 - r2v * ct2;
    sx += dxv[e]; sy += dyv[e]; sz += dzv[e];
  }

  *reinterpret_cast<float4*>(dx + gidx)     = make_float4(dxv[0], dxv[1], dxv[2], dxv[3]);
  *reinterpret_cast<float4*>(dx + gidx + 4) = make_float4(dxv[4], dxv[5], dxv[6], dxv[7]);
  *reinterpret_cast<float4*>(dy + gidx)     = make_float4(dyv[0], dyv[1], dyv[2], dyv[3]);
  *reinterpret_cast<float4*>(dy + gidx + 4) = make_float4(dyv[4], dyv[5], dyv[6], dyv[7]);
  *reinterpret_cast<float4*>(dz + gidx)     = make_float4(dzv[0], dzv[1], dzv[2], dzv[3]);
  *reinterpret_cast<float4*>(dz + gidx + 4) = make_float4(dzv[4], dzv[5], dzv[6], dzv[7]);

  #pragma unroll
  for (int off = 32; off > 0; off >>= 1) {
    sx += __shfl_down(sx, off, 64);
    sy += __shfl_down(sy, off, 64);
    sz += __shfl_down(sz, off, 64);
  }
  __shared__ float wtot[3][A_NW];
  if (lane == 0) { wtot[0][wave] = sx; wtot[1][wave] = sy; wtot[2][wave] = sz; }
  __syncthreads();
  if (t == 0) {
    float ax = 0.f, ay = 0.f, az = 0.f;
    #pragma unroll
    for (int w = 0; w < A_NW; ++w) { ax += wtot[0][w]; ay += wtot[1][w]; az += wtot[2][w]; }
    agg[blk] = make_float4(ax, ay, az, 0.f);
  }
}

__global__ __launch_bounds__(A_THREADS) void k2_scan(
    const float* __restrict__ o3, const float* __restrict__ o2,
    const float4* __restrict__ agg, const float* __restrict__ dx,
    const float* __restrict__ dy, const float* __restrict__ dz,
    float* __restrict__ partial) {
  const int blk = blockIdx.x;
  const int b = blk >> 3;
  const int c = blk & (A_NCH - 1);
  const int t = threadIdx.x;
  const int lane = t & 63;
  const int wave = t >> 6;

  const int idx = c * A_CHUNK + t * A_EPT;
  const size_t gidx = (size_t)b * NPTS + idx;

  float4 DX[2], DY[2], DZ[2];
  #pragma unroll
  for (int g = 0; g < 2; ++g) {
    DX[g] = ld4(dx + gidx + 4 * g);
    DY[g] = ld4(dy + gidx + 4 * g);
    DZ[g] = ld4(dz + gidx + 4 * g);
  }

  const float ox = o3[b * 3 + 0] - o2[b * 3 + 0];
  const float oy = o3[b * 3 + 1] - o2[b * 3 + 1];
  const float oz = o3[b * 3 + 2] - o2[b * 3 + 2];
  float carx = ox, cary = oy, carz = oz;
  for (int cc = 0; cc < c; ++cc) {
    float4 a = agg[(b << 3) + cc];
    carx += a.x; cary += a.y; carz += a.z;
  }

  float px[A_EPT], py[A_EPT], pz[A_EPT];
  float sx = 0.f, sy = 0.f, sz = 0.f;
  #pragma unroll
  for (int e = 0; e < A_EPT; ++e) {
    const int g = e >> 2, k = e & 3;
    sx += ((const float*)&DX[g])[k]; px[e] = sx;
    sy += ((const float*)&DY[g])[k]; py[e] = sy;
    sz += ((const float*)&DZ[g])[k]; pz[e] = sz;
  }

  float ix = sx, iy = sy, iz = sz;
  #pragma unroll
  for (int off = 1; off < 64; off <<= 1) {
    float ax = __shfl_up(ix, off, 64);
    float ay = __shfl_up(iy, off, 64);
    float az = __shfl_up(iz, off, 64);
    if (lane >= off) { ix += ax; iy += ay; iz += az; }
  }
  const float exs = ix - sx, eys = iy - sy, ezs = iz - sz;

  __shared__ float wtot[3][A_NW];
  __shared__ float redbuf[A_NW];
  if (lane == 63) { wtot[0][wave] = ix; wtot[1][wave] = iy; wtot[2][wave] = iz; }
  __syncthreads();

  float wx = 0.f, wy = 0.f, wz = 0.f;
  #pragma unroll
  for (int w = 0; w < A_NW; ++w) {
    if (w < wave) { wx += wtot[0][w]; wy += wtot[1][w]; wz += wtot[2][w]; }
  }

  const float bx = carx + wx + exs;
  const float by = cary + wy + eys;
  const float bz = carz + wz + ezs;

  float acc = 0.f;
  #pragma unroll
  for (int e = 0; e < A_EPT; ++e) {
    acc += fabsf(bx + px[e]) + fabsf(by + py[e]) + fabsf(bz + pz[e]);
  }
  if (c == 0 && t == 0) acc += fabsf(ox) + fabsf(oy) + fabsf(oz);

  #pragma unroll
  for (int off = 32; off > 0; off >>= 1) acc += __shfl_down(acc, off, 64);
  if (lane == 0) redbuf[wave] = acc;
  __syncthreads();
  if (t == 0) {
    float s = 0.f;
    #pragma unroll
    for (int w = 0; w < A_NW; ++w) s += redbuf[w];
    partial[blk] = s;
  }
}

__global__ __launch_bounds__(256) void k3_final(const float* __restrict__ partial,
                                                float* __restrict__ out) {
  const int t = threadIdx.x;
  const int lane = t & 63;
  const int wave = t >> 6;
  float s = 0.f;
  #pragma unroll
  for (int i = 0; i < A_NBLK / 256; ++i) s += partial[i * 256 + t];
  #pragma unroll
  for (int off = 32; off > 0; off >>= 1) s += __shfl_down(s, off, 64);
  __shared__ float red[4];
  if (lane == 0) red[wave] = s;
  __syncthreads();
  if (t == 0) {
    float tot = red[0] + red[1] + red[2] + red[3];
    out[0] = tot * (1.0f / (float)(NPTS + 1));
  }
}

extern "C" void kernel_launch(void* const* d_in, const int* in_sizes, int n_in,
                              void* d_out, int out_size, void* d_ws, size_t ws_size,
                              hipStream_t stream) {
  const float* o3 = (const float*)d_in[0];  // origin_3D      (B,3,1)
  const float* s3 = (const float*)d_in[1];  // spherical_3D   (B,3,N)
  const float* o2 = (const float*)d_in[2];  // origin_2D      (B,3,1)
  const float* s2 = (const float*)d_in[3];  // spherical_2D   (B,3,N)
  const float* df = (const float*)d_in[4];  // deformation    (B,2,N)
  float* out = (float*)d_out;
  char* ws = (char*)d_ws;

  // out accumulates via atomicAdd in the coop path; zero it every launch.
  hipMemsetAsync(out, 0, sizeof(float) * out_size, stream);

  // Try the cooperative single-pass first (needs only 16 KB of ws).
  float4* cagg = (float4*)ws;
  void* args[] = {(void*)&o3, (void*)&s3, (void*)&o2, (void*)&s2,
                  (void*)&df, (void*)&cagg, (void*)&out};
  hipError_t err = hipLaunchCooperativeKernel(
      reinterpret_cast<const void*>(&coop_kernel),
      dim3(C_NBLK), dim3(C_THREADS), args, 0, stream);
  if (err == hipSuccess) return;

  // Fallback: proven Round-5 three-kernel pipeline.
  if (ws_size >= WS_NEED) {
    float4* agg     = (float4*)(ws + WS_AGG_OFF);
    float*  partial = (float*)(ws + WS_PARTIAL_OFF);
    float*  dx      = (float*)(ws + WS_DX_OFF);
    float*  dy      = dx + NPOINTS;
    float*  dz      = dy + NPOINTS;
    k1_diff<<<A_NBLK, A_THREADS, 0, stream>>>(s3, s2, df, agg, dx, dy, dz);
    k2_scan<<<A_NBLK, A_THREADS, 0, stream>>>(o3, o2, agg, dx, dy, dz, partial);
    k3_final<<<1, 256, 0, stream>>>(partial, out);
  }
}

// Round 7
// 38.307 us; speedup vs baseline: 4.4879x; 4.4879x over previous
//
#include <hip/hip_runtime.h>

#define NPTS 16384
#define NBATCH 256

__device__ __forceinline__ float4 ld4(const float* p) {
  return *reinterpret_cast<const float4*>(p);
}

// bf16 round-to-nearest-even (finite values only)
__device__ __forceinline__ unsigned int f2bf(float f) {
  unsigned int x = __float_as_uint(f);
  return (x + 0x7FFFu + ((x >> 16) & 1u)) >> 16;
}
__device__ __forceinline__ float bf2f(unsigned int u) {
  return __uint_as_float(u << 16);
}

// ================= three-kernel pipeline, bf16 intermediate ==============
constexpr int A_THREADS = 256;               // 4 waves
constexpr int A_EPT     = 8;                 // 8 points per thread
constexpr int A_CHUNK   = A_THREADS * A_EPT; // 2048 points per block
constexpr int A_NCH     = NPTS / A_CHUNK;    // 8 chunks per row
constexpr int A_NBLK    = NBATCH * A_NCH;    // 2048 blocks
constexpr int A_NW      = A_THREADS / 64;    // 4
constexpr size_t NPOINTS = (size_t)NBATCH * NPTS;          // 4,194,304
constexpr size_t WS_AGG_OFF     = 0;                        // float4[2048] = 32 KB
constexpr size_t WS_PARTIAL_OFF = 32 * 1024;                // float[2048]  =  8 KB
constexpr size_t WS_D_OFF       = 64 * 1024;                // 3 x bf16[NPOINTS] = 24 MB
constexpr size_t WS_NEED = WS_D_OFF + 3 * NPOINTS * sizeof(unsigned short);

// K1: read inputs once, trig, store bf16 diffs + fp32 per-chunk aggregates.
__global__ __launch_bounds__(A_THREADS) void k1_diff(
    const float* __restrict__ s3, const float* __restrict__ s2,
    const float* __restrict__ df, float4* __restrict__ agg,
    unsigned short* __restrict__ dbx, unsigned short* __restrict__ dby,
    unsigned short* __restrict__ dbz) {
  const int blk = blockIdx.x;
  const int b = blk >> 3;
  const int c = blk & (A_NCH - 1);
  const int t = threadIdx.x;
  const int lane = t & 63;
  const int wave = t >> 6;

  const float* r3p = s3 + (size_t)b * 3 * NPTS;
  const float* t3p = r3p + NPTS;
  const float* p3p = r3p + 2 * NPTS;
  const float* r2p = s2 + (size_t)b * 3 * NPTS;
  const float* t2p = r2p + NPTS;
  const float* p2p = r2p + 2 * NPTS;
  const float* dtp = df + (size_t)b * 2 * NPTS;
  const float* dpp = dtp + NPTS;

  const int idx = c * A_CHUNK + t * A_EPT;          // within-row point index
  const size_t gidx = (size_t)b * NPTS + idx;       // global point index

  float4 R3[2], T3[2], P3[2], R2[2], T2[2], P2[2], DT[2], DP[2];
  #pragma unroll
  for (int g = 0; g < 2; ++g) {
    R3[g] = ld4(r3p + idx + 4 * g);
    T3[g] = ld4(t3p + idx + 4 * g);
    P3[g] = ld4(p3p + idx + 4 * g);
    R2[g] = ld4(r2p + idx + 4 * g);
    T2[g] = ld4(t2p + idx + 4 * g);
    P2[g] = ld4(p2p + idx + 4 * g);
    DT[g] = ld4(dtp + idx + 4 * g);
    DP[g] = ld4(dpp + idx + 4 * g);
  }

  float dxv[A_EPT], dyv[A_EPT], dzv[A_EPT];
  float sx = 0.f, sy = 0.f, sz = 0.f;
  #pragma unroll
  for (int e = 0; e < A_EPT; ++e) {
    const int g = e >> 2, k = e & 3;
    float r3v = ((const float*)&R3[g])[k];
    float th3 = ((const float*)&T3[g])[k] + ((const float*)&DT[g])[k];
    float ph3 = ((const float*)&P3[g])[k] + ((const float*)&DP[g])[k];
    float r2v = ((const float*)&R2[g])[k];
    float th2 = ((const float*)&T2[g])[k];
    float ph2 = ((const float*)&P2[g])[k];
    float st3 = __sinf(th3), ct3 = __cosf(th3);
    float sp3 = __sinf(ph3), cp3 = __cosf(ph3);
    float st2 = __sinf(th2), ct2 = __cosf(th2);
    float sp2 = __sinf(ph2), cp2 = __cosf(ph2);
    dxv[e] = r3v * st3 * cp3 - r2v * st2 * cp2;
    dyv[e] = r3v * st3 * sp3 - r2v * st2 * sp2;
    dzv[e] = r3v * ct3 - r2v * ct2;
    sx += dxv[e]; sy += dyv[e]; sz += dzv[e];
  }

  // pack 8 diffs per component into one uint4 (8 x bf16 = 16 B) and store
  uint4 ux, uy, uz;
  ux.x = f2bf(dxv[0]) | (f2bf(dxv[1]) << 16);
  ux.y = f2bf(dxv[2]) | (f2bf(dxv[3]) << 16);
  ux.z = f2bf(dxv[4]) | (f2bf(dxv[5]) << 16);
  ux.w = f2bf(dxv[6]) | (f2bf(dxv[7]) << 16);
  uy.x = f2bf(dyv[0]) | (f2bf(dyv[1]) << 16);
  uy.y = f2bf(dyv[2]) | (f2bf(dyv[3]) << 16);
  uy.z = f2bf(dyv[4]) | (f2bf(dyv[5]) << 16);
  uy.w = f2bf(dyv[6]) | (f2bf(dyv[7]) << 16);
  uz.x = f2bf(dzv[0]) | (f2bf(dzv[1]) << 16);
  uz.y = f2bf(dzv[2]) | (f2bf(dzv[3]) << 16);
  uz.z = f2bf(dzv[4]) | (f2bf(dzv[5]) << 16);
  uz.w = f2bf(dzv[6]) | (f2bf(dzv[7]) << 16);
  *reinterpret_cast<uint4*>(dbx + gidx) = ux;
  *reinterpret_cast<uint4*>(dby + gidx) = uy;
  *reinterpret_cast<uint4*>(dbz + gidx) = uz;

  // NOTE: aggregate is the fp32 sum of the EXACT diffs; k2 scans the bf16
  // diffs. Tiny (random-walk) inconsistency is harmless after the /N.
  #pragma unroll
  for (int off = 32; off > 0; off >>= 1) {
    sx += __shfl_down(sx, off, 64);
    sy += __shfl_down(sy, off, 64);
    sz += __shfl_down(sz, off, 64);
  }
  __shared__ float wtot[3][A_NW];
  if (lane == 0) { wtot[0][wave] = sx; wtot[1][wave] = sy; wtot[2][wave] = sz; }
  __syncthreads();
  if (t == 0) {
    float ax = 0.f, ay = 0.f, az = 0.f;
    #pragma unroll
    for (int w = 0; w < A_NW; ++w) { ax += wtot[0][w]; ay += wtot[1][w]; az += wtot[2][w]; }
    agg[blk] = make_float4(ax, ay, az, 0.f);
  }
}

// K2: scan the bf16 diffs (L3-hot), plain-store per-block partial sums.
__global__ __launch_bounds__(A_THREADS) void k2_scan(
    const float* __restrict__ o3, const float* __restrict__ o2,
    const float4* __restrict__ agg, const unsigned short* __restrict__ dbx,
    const unsigned short* __restrict__ dby, const unsigned short* __restrict__ dbz,
    float* __restrict__ partial) {
  const int blk = blockIdx.x;
  const int b = blk >> 3;
  const int c = blk & (A_NCH - 1);
  const int t = threadIdx.x;
  const int lane = t & 63;
  const int wave = t >> 6;

  const int idx = c * A_CHUNK + t * A_EPT;
  const size_t gidx = (size_t)b * NPTS + idx;

  const uint4 ux = *reinterpret_cast<const uint4*>(dbx + gidx);
  const uint4 uy = *reinterpret_cast<const uint4*>(dby + gidx);
  const uint4 uz = *reinterpret_cast<const uint4*>(dbz + gidx);

  // carry = origin diff + preceding chunk aggregates (uniform, L2-hot)
  const float ox = o3[b * 3 + 0] - o2[b * 3 + 0];
  const float oy = o3[b * 3 + 1] - o2[b * 3 + 1];
  const float oz = o3[b * 3 + 2] - o2[b * 3 + 2];
  float carx = ox, cary = oy, carz = oz;
  for (int cc = 0; cc < c; ++cc) {
    float4 a = agg[(b << 3) + cc];
    carx += a.x; cary += a.y; carz += a.z;
  }

  const unsigned int* px4 = reinterpret_cast<const unsigned int*>(&ux);
  const unsigned int* py4 = reinterpret_cast<const unsigned int*>(&uy);
  const unsigned int* pz4 = reinterpret_cast<const unsigned int*>(&uz);

  float px[A_EPT], py[A_EPT], pz[A_EPT];
  float sx = 0.f, sy = 0.f, sz = 0.f;
  #pragma unroll
  for (int e = 0; e < A_EPT; ++e) {
    const int w = e >> 1;
    const unsigned int sh = (e & 1) ? 16u : 0u;
    sx += bf2f((px4[w] >> sh) & 0xFFFFu); px[e] = sx;
    sy += bf2f((py4[w] >> sh) & 0xFFFFu); py[e] = sy;
    sz += bf2f((pz4[w] >> sh) & 0xFFFFu); pz[e] = sz;
  }

  // wave-level inclusive scan of thread totals
  float ix = sx, iy = sy, iz = sz;
  #pragma unroll
  for (int off = 1; off < 64; off <<= 1) {
    float ax = __shfl_up(ix, off, 64);
    float ay = __shfl_up(iy, off, 64);
    float az = __shfl_up(iz, off, 64);
    if (lane >= off) { ix += ax; iy += ay; iz += az; }
  }
  const float exs = ix - sx, eys = iy - sy, ezs = iz - sz;

  __shared__ float wtot[3][A_NW];
  __shared__ float redbuf[A_NW];
  if (lane == 63) { wtot[0][wave] = ix; wtot[1][wave] = iy; wtot[2][wave] = iz; }
  __syncthreads();

  float wx = 0.f, wy = 0.f, wz = 0.f;
  #pragma unroll
  for (int w = 0; w < A_NW; ++w) {
    if (w < wave) { wx += wtot[0][w]; wy += wtot[1][w]; wz += wtot[2][w]; }
  }

  const float bx = carx + wx + exs;
  const float by = cary + wy + eys;
  const float bz = carz + wz + ezs;

  float acc = 0.f;
  #pragma unroll
  for (int e = 0; e < A_EPT; ++e) {
    acc += fabsf(bx + px[e]) + fabsf(by + py[e]) + fabsf(bz + pz[e]);
  }
  if (c == 0 && t == 0) acc += fabsf(ox) + fabsf(oy) + fabsf(oz);  // j=0 term

  #pragma unroll
  for (int off = 32; off > 0; off >>= 1) acc += __shfl_down(acc, off, 64);
  if (lane == 0) redbuf[wave] = acc;
  __syncthreads();
  if (t == 0) {
    float s = 0.f;
    #pragma unroll
    for (int w = 0; w < A_NW; ++w) s += redbuf[w];
    partial[blk] = s;
  }
}

// K3: reduce 2048 partials, write the loss (plain store, no memset needed).
__global__ __launch_bounds__(256) void k3_final(const float* __restrict__ partial,
                                                float* __restrict__ out) {
  const int t = threadIdx.x;
  const int lane = t & 63;
  const int wave = t >> 6;
  float s = 0.f;
  #pragma unroll
  for (int i = 0; i < A_NBLK / 256; ++i) s += partial[i * 256 + t];
  #pragma unroll
  for (int off = 32; off > 0; off >>= 1) s += __shfl_down(s, off, 64);
  __shared__ float red[4];
  if (lane == 0) red[wave] = s;
  __syncthreads();
  if (t == 0) {
    float tot = red[0] + red[1] + red[2] + red[3];
    out[0] = tot * (1.0f / (float)(NPTS + 1));
  }
}

extern "C" void kernel_launch(void* const* d_in, const int* in_sizes, int n_in,
                              void* d_out, int out_size, void* d_ws, size_t ws_size,
                              hipStream_t stream) {
  const float* o3 = (const float*)d_in[0];  // origin_3D      (B,3,1)
  const float* s3 = (const float*)d_in[1];  // spherical_3D   (B,3,N)
  const float* o2 = (const float*)d_in[2];  // origin_2D      (B,3,1)
  const float* s2 = (const float*)d_in[3];  // spherical_2D   (B,3,N)
  const float* df = (const float*)d_in[4];  // deformation    (B,2,N)
  float* out = (float*)d_out;
  char* ws = (char*)d_ws;

  float4*         agg     = (float4*)(ws + WS_AGG_OFF);
  float*          partial = (float*)(ws + WS_PARTIAL_OFF);
  unsigned short* dbx     = (unsigned short*)(ws + WS_D_OFF);
  unsigned short* dby     = dbx + NPOINTS;
  unsigned short* dbz     = dby + NPOINTS;

  k1_diff<<<A_NBLK, A_THREADS, 0, stream>>>(s3, s2, df, agg, dbx, dby, dbz);
  k2_scan<<<A_NBLK, A_THREADS, 0, stream>>>(o3, o2, agg, dbx, dby, dbz, partial);
  k3_final<<<1, 256, 0, stream>>>(partial, out);
}

// Round 8
// 34.738 us; speedup vs baseline: 4.9488x; 1.1027x over previous
//
#include <hip/hip_runtime.h>

#define NPTS 16384
#define NBATCH 256
constexpr int THREADS = 1024;            // 16 waves; one block per row/CU
constexpr int EPT     = 16;              // 16 points/thread -> 1024*16 = 16384
constexpr int NW      = THREADS / 64;    // 16 waves

__device__ __forceinline__ float4 ld4(const float* p) {
  return *reinterpret_cast<const float4*>(p);
}

// One block = one batch row. Single pass: stream+trig+thread-prefix (regs),
// block scan (2 barriers), carry = origin diff (known immediately), abs-sum.
// No intermediate global traffic at all.
__global__ __launch_bounds__(THREADS, 4) void row_loss_kernel(
    const float* __restrict__ o3, const float* __restrict__ s3,
    const float* __restrict__ o2, const float* __restrict__ s2,
    const float* __restrict__ df, float* __restrict__ out) {
  const int b = blockIdx.x;
  const int t = threadIdx.x;
  const int lane = t & 63;
  const int wave = t >> 6;

  const float* r3p = s3 + (size_t)b * 3 * NPTS;
  const float* t3p = r3p + NPTS;
  const float* p3p = r3p + 2 * NPTS;
  const float* r2p = s2 + (size_t)b * 3 * NPTS;
  const float* t2p = r2p + NPTS;
  const float* p2p = r2p + 2 * NPTS;
  const float* dtp = df + (size_t)b * 2 * NPTS;
  const float* dpp = dtp + NPTS;

  const int idx = t * EPT;   // contiguous 16-point segment per thread

  // ---- Phase 1: stream inputs, trig, thread-local inclusive prefix ----
  float px[EPT], py[EPT], pz[EPT];
  float sx = 0.f, sy = 0.f, sz = 0.f;
  #pragma unroll
  for (int g = 0; g < EPT / 4; ++g) {
    float4 R3 = ld4(r3p + idx + 4 * g), T3 = ld4(t3p + idx + 4 * g);
    float4 P3 = ld4(p3p + idx + 4 * g), R2 = ld4(r2p + idx + 4 * g);
    float4 T2 = ld4(t2p + idx + 4 * g), P2 = ld4(p2p + idx + 4 * g);
    float4 DT = ld4(dtp + idx + 4 * g), DP = ld4(dpp + idx + 4 * g);
    #pragma unroll
    for (int k = 0; k < 4; ++k) {
      const int e = 4 * g + k;
      float r3v = ((const float*)&R3)[k];
      float th3 = ((const float*)&T3)[k] + ((const float*)&DT)[k];
      float ph3 = ((const float*)&P3)[k] + ((const float*)&DP)[k];
      float r2v = ((const float*)&R2)[k];
      float th2 = ((const float*)&T2)[k];
      float ph2 = ((const float*)&P2)[k];
      float st3 = __sinf(th3), ct3 = __cosf(th3);
      float sp3 = __sinf(ph3), cp3 = __cosf(ph3);
      float st2 = __sinf(th2), ct2 = __cosf(th2);
      float sp2 = __sinf(ph2), cp2 = __cosf(ph2);
      sx += r3v * st3 * cp3 - r2v * st2 * cp2; px[e] = sx;
      sy += r3v * st3 * sp3 - r2v * st2 * sp2; py[e] = sy;
      sz += r3v * ct3 - r2v * ct2;             pz[e] = sz;
    }
  }

  // ---- Phase 2: block-wide scan of per-thread totals ----
  float ix = sx, iy = sy, iz = sz;
  #pragma unroll
  for (int off = 1; off < 64; off <<= 1) {
    float ax = __shfl_up(ix, off, 64);
    float ay = __shfl_up(iy, off, 64);
    float az = __shfl_up(iz, off, 64);
    if (lane >= off) { ix += ax; iy += ay; iz += az; }
  }
  const float exs = ix - sx, eys = iy - sy, ezs = iz - sz;  // exclusive

  __shared__ float wtot[3][NW];
  __shared__ float redbuf[NW];
  if (lane == 63) { wtot[0][wave] = ix; wtot[1][wave] = iy; wtot[2][wave] = iz; }
  __syncthreads();

  float wx = 0.f, wy = 0.f, wz = 0.f;   // offset of previous waves
  #pragma unroll
  for (int w = 0; w < NW; ++w) {
    if (w < wave) { wx += wtot[0][w]; wy += wtot[1][w]; wz += wtot[2][w]; }
  }

  // carry for the whole row = origin diff (uniform scalar loads, L2-hot)
  const float ox = o3[b * 3 + 0] - o2[b * 3 + 0];
  const float oy = o3[b * 3 + 1] - o2[b * 3 + 1];
  const float oz = o3[b * 3 + 2] - o2[b * 3 + 2];

  const float bx = ox + wx + exs;
  const float by = oy + wy + eys;
  const float bz = oz + wz + ezs;

  // ---- Phase 3: abs over in-register prefixes ----
  float acc = 0.f;
  #pragma unroll
  for (int e = 0; e < EPT; ++e) {
    acc += fabsf(bx + px[e]) + fabsf(by + py[e]) + fabsf(bz + pz[e]);
  }
  if (t == 0) acc += fabsf(ox) + fabsf(oy) + fabsf(oz);  // j=0 cumsum term

  // ---- block reduction + one atomic per row ----
  #pragma unroll
  for (int off = 32; off > 0; off >>= 1) acc += __shfl_down(acc, off, 64);
  if (lane == 0) redbuf[wave] = acc;
  __syncthreads();
  if (t == 0) {
    float s = 0.f;
    #pragma unroll
    for (int w = 0; w < NW; ++w) s += redbuf[w];
    atomicAdd(out, s * (1.0f / (float)(NPTS + 1)));
  }
}

extern "C" void kernel_launch(void* const* d_in, const int* in_sizes, int n_in,
                              void* d_out, int out_size, void* d_ws, size_t ws_size,
                              hipStream_t stream) {
  const float* o3 = (const float*)d_in[0];  // origin_3D      (B,3,1)
  const float* s3 = (const float*)d_in[1];  // spherical_3D   (B,3,N)
  const float* o2 = (const float*)d_in[2];  // origin_2D      (B,3,1)
  const float* s2 = (const float*)d_in[3];  // spherical_2D   (B,3,N)
  const float* df = (const float*)d_in[4];  // deformation    (B,2,N)
  float* out = (float*)d_out;

  // out accumulates via atomicAdd; harness doesn't re-zero between replays.
  hipMemsetAsync(out, 0, sizeof(float) * out_size, stream);
  row_loss_kernel<<<NBATCH, THREADS, 0, stream>>>(o3, s3, o2, s2, df, out);
}

// Round 9
// 33.774 us; speedup vs baseline: 5.0901x; 1.0285x over previous
//
#include <hip/hip_runtime.h>

#define NPTS 16384
#define NBATCH 256
constexpr int THREADS = 1024;            // 16 waves; one block per row/CU
constexpr int NW      = THREADS / 64;    // 16 waves
// wave w owns points [w*1024, (w+1)*1024); lane i owns 4-pt mini-segments
// at w*1024 + g*256 + i*4, g=0..3  -> every load is 64x16B contiguous.

__device__ __forceinline__ float4 ld4(const float* p) {
  return *reinterpret_cast<const float4*>(p);
}

__global__ __launch_bounds__(THREADS, 4) void row_loss_kernel(
    const float* __restrict__ o3, const float* __restrict__ s3,
    const float* __restrict__ o2, const float* __restrict__ s2,
    const float* __restrict__ df, float* __restrict__ out) {
  const int b = blockIdx.x;
  const int t = threadIdx.x;
  const int lane = t & 63;
  const int wave = t >> 6;

  const float* r3p = s3 + (size_t)b * 3 * NPTS;
  const float* t3p = r3p + NPTS;
  const float* p3p = r3p + 2 * NPTS;
  const float* r2p = s2 + (size_t)b * 3 * NPTS;
  const float* t2p = r2p + NPTS;
  const float* p2p = r2p + 2 * NPTS;
  const float* dtp = df + (size_t)b * 2 * NPTS;
  const float* dpp = dtp + NPTS;

  const int wbase = wave * 1024;

  // ---- Phase 1: coalesced loads, trig, per-mini-segment prefix ----
  float px[4][4], py[4][4], pz[4][4];   // inclusive prefix within mini-seg
  float mx[4], my[4], mz[4];            // mini-segment totals
  #pragma unroll
  for (int g = 0; g < 4; ++g) {
    const int idx = wbase + g * 256 + lane * 4;
    float4 R3 = ld4(r3p + idx), T3 = ld4(t3p + idx);
    float4 P3 = ld4(p3p + idx), R2 = ld4(r2p + idx);
    float4 T2 = ld4(t2p + idx), P2 = ld4(p2p + idx);
    float4 DT = ld4(dtp + idx), DP = ld4(dpp + idx);
    float sx = 0.f, sy = 0.f, sz = 0.f;
    #pragma unroll
    for (int k = 0; k < 4; ++k) {
      float r3v = ((const float*)&R3)[k];
      float th3 = ((const float*)&T3)[k] + ((const float*)&DT)[k];
      float ph3 = ((const float*)&P3)[k] + ((const float*)&DP)[k];
      float r2v = ((const float*)&R2)[k];
      float th2 = ((const float*)&T2)[k];
      float ph2 = ((const float*)&P2)[k];
      float st3 = __sinf(th3), ct3 = __cosf(th3);
      float sp3 = __sinf(ph3), cp3 = __cosf(ph3);
      float st2 = __sinf(th2), ct2 = __cosf(th2);
      float sp2 = __sinf(ph2), cp2 = __cosf(ph2);
      sx += r3v * st3 * cp3 - r2v * st2 * cp2; px[g][k] = sx;
      sy += r3v * st3 * sp3 - r2v * st2 * sp2; py[g][k] = sy;
      sz += r3v * ct3 - r2v * ct2;             pz[g][k] = sz;
    }
    mx[g] = sx; my[g] = sy; mz[g] = sz;
  }

  // ---- Phase 2: wave scan in j-order (g-major, then lane) ----
  float runx = 0.f, runy = 0.f, runz = 0.f;   // wave-running total
  float segx[4], segy[4], segz[4];            // exclusive offset per mini-seg
  #pragma unroll
  for (int g = 0; g < 4; ++g) {
    float ix = mx[g], iy = my[g], iz = mz[g]; // inclusive lane-scan
    #pragma unroll
    for (int off = 1; off < 64; off <<= 1) {
      float ax = __shfl_up(ix, off, 64);
      float ay = __shfl_up(iy, off, 64);
      float az = __shfl_up(iz, off, 64);
      if (lane >= off) { ix += ax; iy += ay; iz += az; }
    }
    segx[g] = runx + ix - mx[g];
    segy[g] = runy + iy - my[g];
    segz[g] = runz + iz - mz[g];
    runx += __shfl(ix, 63, 64);   // broadcast g-subblock total
    runy += __shfl(iy, 63, 64);
    runz += __shfl(iz, 63, 64);
  }

  // ---- Phase 3: block scan over wave totals ----
  __shared__ float wtot[3][NW];
  __shared__ float redbuf[NW];
  if (lane == 0) { wtot[0][wave] = runx; wtot[1][wave] = runy; wtot[2][wave] = runz; }
  __syncthreads();

  float wx = 0.f, wy = 0.f, wz = 0.f;
  #pragma unroll
  for (int w = 0; w < NW; ++w) {
    if (w < wave) { wx += wtot[0][w]; wy += wtot[1][w]; wz += wtot[2][w]; }
  }

  // carry for the whole row = origin diff (uniform scalar loads)
  const float ox = o3[b * 3 + 0] - o2[b * 3 + 0];
  const float oy = o3[b * 3 + 1] - o2[b * 3 + 1];
  const float oz = o3[b * 3 + 2] - o2[b * 3 + 2];

  const float bx = ox + wx, by = oy + wy, bz = oz + wz;

  // ---- Phase 4: abs over in-register prefixes ----
  float acc = 0.f;
  #pragma unroll
  for (int g = 0; g < 4; ++g) {
    const float gx = bx + segx[g], gy = by + segy[g], gz = bz + segz[g];
    #pragma unroll
    for (int k = 0; k < 4; ++k) {
      acc += fabsf(gx + px[g][k]) + fabsf(gy + py[g][k]) + fabsf(gz + pz[g][k]);
    }
  }
  if (t == 0) acc += fabsf(ox) + fabsf(oy) + fabsf(oz);  // j=0 cumsum term

  // ---- block reduction + one atomic per row ----
  #pragma unroll
  for (int off = 32; off > 0; off >>= 1) acc += __shfl_down(acc, off, 64);
  if (lane == 0) redbuf[wave] = acc;
  __syncthreads();
  if (t == 0) {
    float s = 0.f;
    #pragma unroll
    for (int w = 0; w < NW; ++w) s += redbuf[w];
    atomicAdd(out, s * (1.0f / (float)(NPTS + 1)));
  }
}

extern "C" void kernel_launch(void* const* d_in, const int* in_sizes, int n_in,
                              void* d_out, int out_size, void* d_ws, size_t ws_size,
                              hipStream_t stream) {
  const float* o3 = (const float*)d_in[0];  // origin_3D      (B,3,1)
  const float* s3 = (const float*)d_in[1];  // spherical_3D   (B,3,N)
  const float* o2 = (const float*)d_in[2];  // origin_2D      (B,3,1)
  const float* s2 = (const float*)d_in[3];  // spherical_2D   (B,3,N)
  const float* df = (const float*)d_in[4];  // deformation    (B,2,N)
  float* out = (float*)d_out;

  // out accumulates via atomicAdd; harness doesn't re-zero between replays.
  hipMemsetAsync(out, 0, sizeof(float) * out_size, stream);
  row_loss_kernel<<<NBATCH, THREADS, 0, stream>>>(o3, s3, o2, s2, df, out);
}